// Round 6
// baseline (316.658 us; speedup 1.0000x reference)
//
#include <hip/hip_runtime.h>

typedef unsigned short ushort_t;
typedef __attribute__((ext_vector_type(8))) __bf16 bf16x8;
typedef __attribute__((ext_vector_type(4))) float f32x4;
typedef __attribute__((ext_vector_type(4))) int i32x4;
typedef __attribute__((ext_vector_type(4))) unsigned short u16x4;

#define BN_EPS 1e-5f
#define EPAD 136  // epilogue [p][c] c-stride (272B row, 16B-aligned)

__device__ __forceinline__ ushort_t f2bf(float f) {
    union { float f; unsigned u; } v; v.f = f;
    unsigned r = v.u + 0x7FFFu + ((v.u >> 16) & 1u);
    return (ushort_t)(r >> 16);
}
__device__ __forceinline__ float bf2f(ushort_t h) {
    union { unsigned u; float f; } v; v.u = ((unsigned)h) << 16; return v.f;
}

// async 16B global->LDS copy; LDS dst is wave-uniform base (+lane*16 by HW)
__device__ __forceinline__ void async_cp16(const ushort_t* g, ushort_t* l) {
    __builtin_amdgcn_global_load_lds(
        (const __attribute__((address_space(1))) unsigned int*)g,
        (__attribute__((address_space(3))) unsigned int*)l, 16, 0, 0);
}

// ---------------- transpose+cast+GAP: x[b][c][p] f32 -> xt[b][p][c] bf16, partial GAP sums ----------------
__global__ void transpose_gap_kernel(const float* __restrict__ x, ushort_t* __restrict__ xt,
                                     float* __restrict__ gapsum) {
    __shared__ float tile[32][33];
    int b = blockIdx.z, c0 = blockIdx.y * 32, p0 = blockIdx.x * 32;
    int tx = threadIdx.x & 31, ty = threadIdx.x >> 5; // ty 0..7
    float ps[4];
    #pragma unroll
    for (int i = 0; i < 4; ++i) {
        int c = ty + i * 8;
        float v = x[((long)b * 256 + c0 + c) * 1024 + p0 + tx];
        tile[c][tx] = v;
        ps[i] = v;
    }
    #pragma unroll
    for (int off = 16; off; off >>= 1)
        #pragma unroll
        for (int i = 0; i < 4; ++i) ps[i] += __shfl_down(ps[i], off, 32);
    if (tx == 0)
        #pragma unroll
        for (int i = 0; i < 4; ++i) atomicAdd(&gapsum[b * 256 + c0 + ty + i * 8], ps[i]);
    __syncthreads();
    // write: one u16x4 per thread; p = t>>3 (32 rows), c = (t&7)*4
    int t = threadIdx.x;
    int p = t >> 3, cg = (t & 7) * 4;
    u16x4 o;
    #pragma unroll
    for (int i = 0; i < 4; ++i) o[i] = f2bf(tile[cg + i][p]);
    *(u16x4*)(&xt[((long)b * 1024 + p0 + p) * 256 + c0 + cg]) = o;
}

// ---------------- combine (+inline router), both banks in one dispatch ----------------
// k[b][pos][g] = sum_e r[b,e]*w[e][g][pos];  z selects (w1->k1) / (w2->k2)
__global__ void combine_both_kernel(const float* __restrict__ w1, const float* __restrict__ w2,
                                    const float* __restrict__ gapsum,
                                    const float* __restrict__ rw, const float* __restrict__ rb,
                                    ushort_t* __restrict__ k1, ushort_t* __restrict__ k2) {
    const float* w = blockIdx.z ? w2 : w1;
    ushort_t* ko = blockIdx.z ? k2 : k1;
    __shared__ float rsh[16][8];
    int t = threadIdx.x;
    int g = blockIdx.x * 256 + t;  // (o=g>>8, i=g&255)
    int b0 = blockIdx.y * 16;      // 2 b-halves
    if (t < 128) {
        int bb = t >> 3, e = t & 7;
        const float* gp = &gapsum[(b0 + bb) * 256];
        const float* wp = &rw[e * 256];
        float s = 0.f;
        for (int c = 0; c < 256; ++c) s += gp[c] * wp[c];
        rsh[bb][e] = 1.f / (1.f + expf(-(s * (1.f / 1024.f) + rb[e])));
    }
    float wv[8][9];
    #pragma unroll
    for (int e = 0; e < 8; ++e)
        #pragma unroll
        for (int p = 0; p < 9; ++p)
            wv[e][p] = w[((long)e * 65536 + g) * 9 + p];
    __syncthreads();
    for (int bb = 0; bb < 16; ++bb) {
        int b = b0 + bb;
        float rv[8];
        #pragma unroll
        for (int e = 0; e < 8; ++e) rv[e] = rsh[bb][e];
        #pragma unroll
        for (int p = 0; p < 9; ++p) {
            float s = 0.f;
            #pragma unroll
            for (int e = 0; e < 8; ++e) s += rv[e] * wv[e][p];
            ko[((long)(b * 9 + p)) * 65536 + g] = f2bf(s);
        }
    }
}

// single-bank variant (fallback for small ws)
__global__ void combine_single_kernel(const float* __restrict__ w, const float* __restrict__ gapsum,
                                      const float* __restrict__ rw, const float* __restrict__ rb,
                                      ushort_t* __restrict__ ko) {
    __shared__ float rsh[16][8];
    int t = threadIdx.x;
    int g = blockIdx.x * 256 + t;
    int b0 = blockIdx.y * 16;
    if (t < 128) {
        int bb = t >> 3, e = t & 7;
        const float* gp = &gapsum[(b0 + bb) * 256];
        const float* wp = &rw[e * 256];
        float s = 0.f;
        for (int c = 0; c < 256; ++c) s += gp[c] * wp[c];
        rsh[bb][e] = 1.f / (1.f + expf(-(s * (1.f / 1024.f) + rb[e])));
    }
    float wv[8][9];
    #pragma unroll
    for (int e = 0; e < 8; ++e)
        #pragma unroll
        for (int p = 0; p < 9; ++p)
            wv[e][p] = w[((long)e * 65536 + g) * 9 + p];
    __syncthreads();
    for (int bb = 0; bb < 16; ++bb) {
        int b = b0 + bb;
        float rv[8];
        #pragma unroll
        for (int e = 0; e < 8; ++e) rv[e] = rsh[bb][e];
        #pragma unroll
        for (int p = 0; p < 9; ++p) {
            float s = 0.f;
            #pragma unroll
            for (int e = 0; e < 8; ++e) s += rv[e] * wv[e][p];
            ko[((long)(b * 9 + p)) * 65536 + g] = f2bf(s);
        }
    }
}

// ---------------- implicit-GEMM conv 3x3 (pad 1), per-sample weights ----------------
// (round-4 body, verbatim: inline addressing — hoisted-offset variant regressed 40%)
// Grid: 512 linear blocks, XCD-swizzled: id%8 = b%8 so all 16 (nt,mt) siblings of a
// sample land on one XCD => weight/x L2 reuse.
// LDS (16B chunks, XOR-swizzled, written only by global_load_lds):
//   ldsB: halo [6][34] x 8 k-chunks; slot(pi,j)=pi*8+(j^(pi&7))
//   ldsA: 2 x (128 x 8 k-chunks);    slot(row,j)=row*8+(j^(row&7))
// MODE 0: bf16 relu(bn(conv)) [b][p][c];  MODE 1: f32 relu(bn(conv)+resid) [b][c][p]
template <int MODE>
__global__ __launch_bounds__(256, 2) void gemm_conv(
    const ushort_t* __restrict__ xin,   // [B][1024][256] bf16
    const ushort_t* __restrict__ kbank, // [B][9][256][256] bf16
    void* __restrict__ outp,
    const float* __restrict__ gam, const float* __restrict__ bet,
    const float* __restrict__ mu, const float* __restrict__ var,
    const ushort_t* __restrict__ residt) { // [B][1024][256] bf16 (MODE 1 only)
    __shared__ ushort_t smem[29440]; // ldsB [0,13056) ; ldsA [13056,29440)
    ushort_t* ldsB = smem;
    ushort_t* ldsA = smem + 13056;

    const int t = threadIdx.x;
    const int lane = t & 63;
    const int lane15 = lane & 15;
    const int quad = lane >> 4;
    const int wv = t >> 6;
    const int id = blockIdx.x;           // 0..511
    const int q  = id >> 3;
    const int mt = q & 1;
    const int nt = (q >> 1) & 7;
    const int b  = (id & 7) + ((q >> 4) << 3);
    const int h0 = nt * 4;
    const int p0 = nt * 128;
    const int mw0 = (wv >> 1) * 64;
    const int nw0 = (wv & 1) * 64;
    const int wbase = t & ~63;

    f32x4 acc[4][4];
    #pragma unroll
    for (int i = 0; i < 4; ++i)
        #pragma unroll
        for (int j = 0; j < 4; ++j) acc[i][j] = 0.f;

    // pre-zero border cols w'=0,33 (never overwritten)
    if (t < 96) {
        int rix = t >> 3, j = t & 7;
        int pi = (rix >> 1) * 34 + (rix & 1) * 33;
        i32x4 z = 0;
        *(i32x4*)(&ldsB[(pi * 8 + j) * 8]) = z;
    }
    if (nt == 0) { i32x4 z = 0; *(i32x4*)(&ldsB[(8 + t) * 8]) = z; }
    if (nt == 7) { i32x4 z = 0; *(i32x4*)(&ldsB[((5 * 34 + 1) * 8 + t) * 8]) = z; }

    const long xbase = (long)b * 1024 * 256;
    const long kbase = (long)b * 9 * 65536;

    auto stageB = [&](int kc) {
        #pragma unroll
        for (int hh = 0; hh < 6; ++hh) {
            int hg = h0 + hh - 1;
            if (hg < 0 || hg >= 32) continue; // block-uniform
            int ww = t >> 3;
            int pi = hh * 34 + 1 + ww;
            int jd = (t & 7) ^ (pi & 7);
            async_cp16(xin + xbase + (long)(hg * 32 + ww) * 256 + kc * 64 + jd * 8,
                       ldsB + ((hh * 34 + 1) * 8 + wbase) * 8);
        }
    };
    auto stageA = [&](int kc, int pos, int buf) {
        const ushort_t* srcA = kbank + kbase + (long)pos * 65536 + (long)mt * 32768 + kc * 64;
        ushort_t* base = ldsA + buf * 8192;
        #pragma unroll
        for (int it = 0; it < 4; ++it) {
            int s = it * 256 + t;
            int row = s >> 3;
            int k8 = (s & 7) ^ (row & 7);
            async_cp16(srcA + (long)row * 256 + k8 * 8, base + (it * 256 + wbase) * 8);
        }
    };

    stageB(0);
    stageA(0, 0, 0);
    __syncthreads();

    int par = 0;
    for (int kc = 0; kc < 4; ++kc) {
        for (int pos = 0; pos < 9; ++pos) {
            if (!(kc == 3 && pos == 8)) {
                int nk = kc, np = pos + 1;
                if (np == 9) { np = 0; ++nk; }
                stageA(nk, np, par ^ 1);
            }
            const int dh = pos / 3 - 1, dw = pos % 3 - 1;
            const ushort_t* ab = ldsA + par * 8192;
            #pragma unroll
            for (int kb = 0; kb < 2; ++kb) {
                int jk = kb * 4 + quad;
                bf16x8 af[4], bfr[4];
                #pragma unroll
                for (int mf = 0; mf < 4; ++mf) {
                    int row = mw0 + mf * 16 + lane15;
                    af[mf] = *(const bf16x8*)(ab + (row * 8 + (jk ^ (row & 7))) * 8);
                }
                #pragma unroll
                for (int nf = 0; nf < 4; ++nf) {
                    int n = nw0 + nf * 16 + lane15;
                    int pi = ((n >> 5) + 1 + dh) * 34 + (n & 31) + 1 + dw;
                    bfr[nf] = *(const bf16x8*)(&ldsB[(pi * 8 + (jk ^ (pi & 7))) * 8]);
                }
                #pragma unroll
                for (int mf = 0; mf < 4; ++mf)
                    #pragma unroll
                    for (int nf = 0; nf < 4; ++nf)
                        acc[mf][nf] = __builtin_amdgcn_mfma_f32_16x16x32_bf16(af[mf], bfr[nf], acc[mf][nf], 0, 0, 0);
            }
            __syncthreads(); // reads of buf[par] & B done; prefetched A arrived
            if (pos == 8 && kc < 3) { stageB(kc + 1); __syncthreads(); }
            par ^= 1;
        }
    }

    // residual prefetch (MODE 1): bf16 from xt
    u16x4 rres[4][4];
    if (MODE == 1) {
        #pragma unroll
        for (int mf = 0; mf < 4; ++mf)
            #pragma unroll
            for (int nf = 0; nf < 4; ++nf) {
                int p = p0 + nw0 + nf * 16 + lane15;
                int cb = mt * 128 + mw0 + mf * 16 + quad * 4;
                rres[mf][nf] = *(const u16x4*)(residt + ((long)b * 1024 + p) * 256 + cb);
            }
    }

    float sc[4][4], sh[4][4];
    #pragma unroll
    for (int mf = 0; mf < 4; ++mf)
        #pragma unroll
        for (int i = 0; i < 4; ++i) {
            int c = mt * 128 + mw0 + mf * 16 + quad * 4 + i;
            float s = gam[c] * rsqrtf(var[c] + BN_EPS);
            sc[mf][i] = s;
            sh[mf][i] = bet[c] - mu[c] * s;
        }

    if (MODE == 0) {
        __syncthreads();
        ushort_t* ldsE = smem; // [128 p][EPAD c]
        #pragma unroll
        for (int mf = 0; mf < 4; ++mf)
            #pragma unroll
            for (int nf = 0; nf < 4; ++nf) {
                int pl = nw0 + nf * 16 + lane15;
                int cb = mw0 + mf * 16 + quad * 4;
                u16x4 pk;
                #pragma unroll
                for (int i = 0; i < 4; ++i) {
                    float v = acc[mf][nf][i] * sc[mf][i] + sh[mf][i];
                    pk[i] = f2bf(fmaxf(v, 0.f));
                }
                *(u16x4*)(&ldsE[pl * EPAD + cb]) = pk;
            }
        __syncthreads();
        ushort_t* op = (ushort_t*)outp;
        #pragma unroll
        for (int it = 0; it < 8; ++it) {
            int s = t + it * 256;
            int row = s >> 4, l16 = s & 15;
            i32x4 v = *(i32x4*)(&ldsE[row * EPAD + l16 * 8]);
            *(i32x4*)(op + ((long)b * 1024 + p0 + row) * 256 + mt * 128 + l16 * 8) = v;
        }
    } else {
        float* op = (float*)outp;
        #pragma unroll
        for (int mf = 0; mf < 4; ++mf)
            #pragma unroll
            for (int nf = 0; nf < 4; ++nf) {
                int p = p0 + nw0 + nf * 16 + lane15;
                #pragma unroll
                for (int i = 0; i < 4; ++i) {
                    int c = mt * 128 + mw0 + mf * 16 + quad * 4 + i;
                    float v = acc[mf][nf][i] * sc[mf][i] + sh[mf][i] + bf2f(rres[mf][nf][i]);
                    op[((long)b * 256 + c) * 1024 + p] = fmaxf(v, 0.f);
                }
            }
    }
}

extern "C" void kernel_launch(void* const* d_in, const int* in_sizes, int n_in,
                              void* d_out, int out_size, void* d_ws, size_t ws_size,
                              hipStream_t stream) {
    const float* x  = (const float*)d_in[0];
    const float* rw = (const float*)d_in[1];
    const float* rb = (const float*)d_in[2];
    const float* w1 = (const float*)d_in[3];
    const float* w2 = (const float*)d_in[4];
    const float* g1 = (const float*)d_in[5];
    const float* b1 = (const float*)d_in[6];
    const float* m1 = (const float*)d_in[7];
    const float* v1 = (const float*)d_in[8];
    const float* g2 = (const float*)d_in[9];
    const float* b2 = (const float*)d_in[10];
    const float* m2 = (const float*)d_in[11];
    const float* v2 = (const float*)d_in[12];

    // ws: gapsum [0,32KB) | xt 16.78MB | o1 16.78MB | kbuf 37.75MB | [kbuf2 37.75MB if room]
    const size_t XT_OFF  = 32768;
    const size_t O1_OFF  = XT_OFF + (size_t)16777216;
    const size_t KB_OFF  = O1_OFF + (size_t)16777216;
    const size_t KSZ     = (size_t)32 * 9 * 65536 * 2;
    const size_t NEED1   = KB_OFF + KSZ;
    const size_t NEED2   = NEED1 + KSZ;
    if (ws_size < NEED1) return;

    char* ws = (char*)d_ws;
    float* gapsum   = (float*)ws;
    ushort_t* xt    = (ushort_t*)(ws + XT_OFF);
    ushort_t* o1    = (ushort_t*)(ws + O1_OFF);
    ushort_t* kbuf  = (ushort_t*)(ws + KB_OFF);
    ushort_t* kbuf2 = (ushort_t*)(ws + NEED1);

    hipMemsetAsync(gapsum, 0, 32768, stream);
    transpose_gap_kernel<<<dim3(32, 8, 32), 256, 0, stream>>>(x, xt, gapsum);
    if (ws_size >= NEED2) {
        combine_both_kernel<<<dim3(256, 2, 2), 256, 0, stream>>>(w1, w2, gapsum, rw, rb, kbuf, kbuf2);
        gemm_conv<0><<<512, 256, 0, stream>>>(xt, kbuf, (void*)o1, g1, b1, m1, v1, nullptr);
        gemm_conv<1><<<512, 256, 0, stream>>>(o1, kbuf2, d_out, g2, b2, m2, v2, xt);
    } else {
        combine_single_kernel<<<dim3(256, 2), 256, 0, stream>>>(w1, gapsum, rw, rb, kbuf);
        gemm_conv<0><<<512, 256, 0, stream>>>(xt, kbuf, (void*)o1, g1, b1, m1, v1, nullptr);
        combine_single_kernel<<<dim3(256, 2), 256, 0, stream>>>(w2, gapsum, rw, rb, kbuf);
        gemm_conv<1><<<512, 256, 0, stream>>>(o1, kbuf, d_out, g2, b2, m2, v2, xt);
    }
}

// Round 7
// 302.202 us; speedup vs baseline: 1.0478x; 1.0478x over previous
//
#include <hip/hip_runtime.h>

typedef unsigned short ushort_t;
typedef __attribute__((ext_vector_type(8))) __bf16 bf16x8;
typedef __attribute__((ext_vector_type(4))) float f32x4;
typedef __attribute__((ext_vector_type(4))) int i32x4;
typedef __attribute__((ext_vector_type(4))) unsigned short u16x4;

#define BN_EPS 1e-5f
#define EPAD 136  // epilogue [p][c] c-stride (272B row, 16B-aligned)

__device__ __forceinline__ ushort_t f2bf(float f) {
    union { float f; unsigned u; } v; v.f = f;
    unsigned r = v.u + 0x7FFFu + ((v.u >> 16) & 1u);
    return (ushort_t)(r >> 16);
}
__device__ __forceinline__ float bf2f(ushort_t h) {
    union { unsigned u; float f; } v; v.u = ((unsigned)h) << 16; return v.f;
}

// async 16B global->LDS copy; LDS dst is wave-uniform base (+lane*16 by HW)
__device__ __forceinline__ void async_cp16(const ushort_t* g, ushort_t* l) {
    __builtin_amdgcn_global_load_lds(
        (const __attribute__((address_space(1))) unsigned int*)g,
        (__attribute__((address_space(3))) unsigned int*)l, 16, 0, 0);
}

// ---------------- transpose+cast+GAP (round-4 proven form) ----------------
__global__ void transpose_gap_kernel(const float* __restrict__ x, ushort_t* __restrict__ xt,
                                     float* __restrict__ gapsum) {
    __shared__ float tile[32][33];
    int b = blockIdx.z, c0 = blockIdx.y * 32, p0 = blockIdx.x * 32;
    int tx = threadIdx.x & 31, ty = threadIdx.x >> 5; // ty 0..7
    float ps[4];
    #pragma unroll
    for (int i = 0; i < 4; ++i) {
        int c = ty + i * 8;
        float v = x[((long)b * 256 + c0 + c) * 1024 + p0 + tx];
        tile[c][tx] = v;
        ps[i] = v;
    }
    #pragma unroll
    for (int off = 16; off; off >>= 1)
        #pragma unroll
        for (int i = 0; i < 4; ++i) ps[i] += __shfl_down(ps[i], off, 32);
    if (tx == 0)
        #pragma unroll
        for (int i = 0; i < 4; ++i) atomicAdd(&gapsum[b * 256 + c0 + ty + i * 8], ps[i]);
    __syncthreads();
    #pragma unroll
    for (int i = 0; i < 4; ++i) {
        int p = ty + i * 8;
        xt[((long)b * 1024 + p0 + p) * 256 + c0 + tx] = f2bf(tile[tx][p]);
    }
}

// ---------------- combine (+inline router), spill-free p-split ----------------
// k[b][pos][g] = sum_e r[b,e]*w[e][g][pos]
// 2 threads per g: ph=0 -> pos 0..3, ph=1 -> pos 4..8 (max 40 live w-floats, no spill)
// blockIdx.z selects (w1->k1)/(w2->k2); fallback path launches twice with z-grid=1.
__global__ __launch_bounds__(256, 4) void combine_kernel2(
    const float* __restrict__ w1, const float* __restrict__ w2,
    const float* __restrict__ gapsum,
    const float* __restrict__ rw, const float* __restrict__ rb,
    ushort_t* __restrict__ k1, ushort_t* __restrict__ k2) {
    const float* w = blockIdx.z ? w2 : w1;
    ushort_t* ko = blockIdx.z ? k2 : k1;
    __shared__ float rsh[32][8];
    int t = threadIdx.x;
    {   // router: one (b,e) pair per thread
        int bb = t >> 3, e = t & 7;
        const float* gp = &gapsum[bb * 256];
        const float* wp = &rw[e * 256];
        float s = 0.f;
        for (int c = 0; c < 256; ++c) s += gp[c] * wp[c];
        rsh[bb][e] = 1.f / (1.f + expf(-(s * (1.f / 1024.f) + rb[e])));
    }
    int gl = t & 127, ph = t >> 7;          // ph is wave-uniform
    long g = (long)blockIdx.x * 128 + gl;
    int pbase = ph ? 4 : 0, np = ph ? 5 : 4;
    float wv[5][8];                          // [p][e], <=40 live floats
    #pragma unroll
    for (int e = 0; e < 8; ++e)
        for (int p = 0; p < np; ++p)
            wv[p][e] = w[((long)e * 65536 + g) * 9 + pbase + p];
    __syncthreads();
    for (int b = 0; b < 32; ++b) {
        float rv[8];
        #pragma unroll
        for (int e = 0; e < 8; ++e) rv[e] = rsh[b][e];
        #pragma unroll
        for (int p = 0; p < 5; ++p) {
            if (p < np) {                    // wave-uniform predicate
                float s = 0.f;
                #pragma unroll
                for (int e = 0; e < 8; ++e) s += rv[e] * wv[p][e];
                ko[((long)(b * 9 + pbase + p)) * 65536 + g] = f2bf(s);
            }
        }
    }
}

// ---------------- implicit-GEMM conv 3x3 (pad 1), per-sample weights ----------------
// (round-4 body, verbatim — proven 47.5 us, 0 bank conflicts, VGPR 88)
// Grid: 512 linear blocks, XCD-swizzled: id%8 = b%8 so all 16 (nt,mt) siblings of a
// sample land on one XCD => weight/x L2 reuse.
// LDS (16B chunks, XOR-swizzled, written only by global_load_lds):
//   ldsB: halo [6][34] x 8 k-chunks; slot(pi,j)=pi*8+(j^(pi&7))
//   ldsA: 2 x (128 x 8 k-chunks);    slot(row,j)=row*8+(j^(row&7))
// MODE 0: bf16 relu(bn(conv)) [b][p][c];  MODE 1: f32 relu(bn(conv)+resid) [b][c][p]
template <int MODE>
__global__ __launch_bounds__(256, 2) void gemm_conv(
    const ushort_t* __restrict__ xin,   // [B][1024][256] bf16
    const ushort_t* __restrict__ kbank, // [B][9][256][256] bf16
    void* __restrict__ outp,
    const float* __restrict__ gam, const float* __restrict__ bet,
    const float* __restrict__ mu, const float* __restrict__ var,
    const ushort_t* __restrict__ residt) { // [B][1024][256] bf16 (MODE 1 only)
    __shared__ ushort_t smem[29440]; // ldsB [0,13056) ; ldsA [13056,29440)
    ushort_t* ldsB = smem;
    ushort_t* ldsA = smem + 13056;

    const int t = threadIdx.x;
    const int lane = t & 63;
    const int lane15 = lane & 15;
    const int quad = lane >> 4;
    const int wv = t >> 6;
    const int id = blockIdx.x;           // 0..511
    const int q  = id >> 3;
    const int mt = q & 1;
    const int nt = (q >> 1) & 7;
    const int b  = (id & 7) + ((q >> 4) << 3);
    const int h0 = nt * 4;
    const int p0 = nt * 128;
    const int mw0 = (wv >> 1) * 64;
    const int nw0 = (wv & 1) * 64;
    const int wbase = t & ~63;

    f32x4 acc[4][4];
    #pragma unroll
    for (int i = 0; i < 4; ++i)
        #pragma unroll
        for (int j = 0; j < 4; ++j) acc[i][j] = 0.f;

    // pre-zero border cols w'=0,33 (never overwritten)
    if (t < 96) {
        int rix = t >> 3, j = t & 7;
        int pi = (rix >> 1) * 34 + (rix & 1) * 33;
        i32x4 z = 0;
        *(i32x4*)(&ldsB[(pi * 8 + j) * 8]) = z;
    }
    if (nt == 0) { i32x4 z = 0; *(i32x4*)(&ldsB[(8 + t) * 8]) = z; }
    if (nt == 7) { i32x4 z = 0; *(i32x4*)(&ldsB[((5 * 34 + 1) * 8 + t) * 8]) = z; }

    const long xbase = (long)b * 1024 * 256;
    const long kbase = (long)b * 9 * 65536;

    auto stageB = [&](int kc) {
        #pragma unroll
        for (int hh = 0; hh < 6; ++hh) {
            int hg = h0 + hh - 1;
            if (hg < 0 || hg >= 32) continue; // block-uniform
            int ww = t >> 3;
            int pi = hh * 34 + 1 + ww;
            int jd = (t & 7) ^ (pi & 7);
            async_cp16(xin + xbase + (long)(hg * 32 + ww) * 256 + kc * 64 + jd * 8,
                       ldsB + ((hh * 34 + 1) * 8 + wbase) * 8);
        }
    };
    auto stageA = [&](int kc, int pos, int buf) {
        const ushort_t* srcA = kbank + kbase + (long)pos * 65536 + (long)mt * 32768 + kc * 64;
        ushort_t* base = ldsA + buf * 8192;
        #pragma unroll
        for (int it = 0; it < 4; ++it) {
            int s = it * 256 + t;
            int row = s >> 3;
            int k8 = (s & 7) ^ (row & 7);
            async_cp16(srcA + (long)row * 256 + k8 * 8, base + (it * 256 + wbase) * 8);
        }
    };

    stageB(0);
    stageA(0, 0, 0);
    __syncthreads();

    int par = 0;
    for (int kc = 0; kc < 4; ++kc) {
        for (int pos = 0; pos < 9; ++pos) {
            if (!(kc == 3 && pos == 8)) {
                int nk = kc, np = pos + 1;
                if (np == 9) { np = 0; ++nk; }
                stageA(nk, np, par ^ 1);
            }
            const int dh = pos / 3 - 1, dw = pos % 3 - 1;
            const ushort_t* ab = ldsA + par * 8192;
            #pragma unroll
            for (int kb = 0; kb < 2; ++kb) {
                int jk = kb * 4 + quad;
                bf16x8 af[4], bfr[4];
                #pragma unroll
                for (int mf = 0; mf < 4; ++mf) {
                    int row = mw0 + mf * 16 + lane15;
                    af[mf] = *(const bf16x8*)(ab + (row * 8 + (jk ^ (row & 7))) * 8);
                }
                #pragma unroll
                for (int nf = 0; nf < 4; ++nf) {
                    int n = nw0 + nf * 16 + lane15;
                    int pi = ((n >> 5) + 1 + dh) * 34 + (n & 31) + 1 + dw;
                    bfr[nf] = *(const bf16x8*)(&ldsB[(pi * 8 + (jk ^ (pi & 7))) * 8]);
                }
                #pragma unroll
                for (int mf = 0; mf < 4; ++mf)
                    #pragma unroll
                    for (int nf = 0; nf < 4; ++nf)
                        acc[mf][nf] = __builtin_amdgcn_mfma_f32_16x16x32_bf16(af[mf], bfr[nf], acc[mf][nf], 0, 0, 0);
            }
            __syncthreads(); // reads of buf[par] & B done; prefetched A arrived
            if (pos == 8 && kc < 3) { stageB(kc + 1); __syncthreads(); }
            par ^= 1;
        }
    }

    // residual prefetch (MODE 1): bf16 from xt
    u16x4 rres[4][4];
    if (MODE == 1) {
        #pragma unroll
        for (int mf = 0; mf < 4; ++mf)
            #pragma unroll
            for (int nf = 0; nf < 4; ++nf) {
                int p = p0 + nw0 + nf * 16 + lane15;
                int cb = mt * 128 + mw0 + mf * 16 + quad * 4;
                rres[mf][nf] = *(const u16x4*)(residt + ((long)b * 1024 + p) * 256 + cb);
            }
    }

    float sc[4][4], sh[4][4];
    #pragma unroll
    for (int mf = 0; mf < 4; ++mf)
        #pragma unroll
        for (int i = 0; i < 4; ++i) {
            int c = mt * 128 + mw0 + mf * 16 + quad * 4 + i;
            float s = gam[c] * rsqrtf(var[c] + BN_EPS);
            sc[mf][i] = s;
            sh[mf][i] = bet[c] - mu[c] * s;
        }

    if (MODE == 0) {
        __syncthreads();
        ushort_t* ldsE = smem; // [128 p][EPAD c]
        #pragma unroll
        for (int mf = 0; mf < 4; ++mf)
            #pragma unroll
            for (int nf = 0; nf < 4; ++nf) {
                int pl = nw0 + nf * 16 + lane15;
                int cb = mw0 + mf * 16 + quad * 4;
                u16x4 pk;
                #pragma unroll
                for (int i = 0; i < 4; ++i) {
                    float v = acc[mf][nf][i] * sc[mf][i] + sh[mf][i];
                    pk[i] = f2bf(fmaxf(v, 0.f));
                }
                *(u16x4*)(&ldsE[pl * EPAD + cb]) = pk;
            }
        __syncthreads();
        ushort_t* op = (ushort_t*)outp;
        #pragma unroll
        for (int it = 0; it < 8; ++it) {
            int s = t + it * 256;
            int row = s >> 4, l16 = s & 15;
            i32x4 v = *(i32x4*)(&ldsE[row * EPAD + l16 * 8]);
            *(i32x4*)(op + ((long)b * 1024 + p0 + row) * 256 + mt * 128 + l16 * 8) = v;
        }
    } else {
        float* op = (float*)outp;
        #pragma unroll
        for (int mf = 0; mf < 4; ++mf)
            #pragma unroll
            for (int nf = 0; nf < 4; ++nf) {
                int p = p0 + nw0 + nf * 16 + lane15;
                #pragma unroll
                for (int i = 0; i < 4; ++i) {
                    int c = mt * 128 + mw0 + mf * 16 + quad * 4 + i;
                    float v = acc[mf][nf][i] * sc[mf][i] + sh[mf][i] + bf2f(rres[mf][nf][i]);
                    op[((long)b * 256 + c) * 1024 + p] = fmaxf(v, 0.f);
                }
            }
    }
}

extern "C" void kernel_launch(void* const* d_in, const int* in_sizes, int n_in,
                              void* d_out, int out_size, void* d_ws, size_t ws_size,
                              hipStream_t stream) {
    const float* x  = (const float*)d_in[0];
    const float* rw = (const float*)d_in[1];
    const float* rb = (const float*)d_in[2];
    const float* w1 = (const float*)d_in[3];
    const float* w2 = (const float*)d_in[4];
    const float* g1 = (const float*)d_in[5];
    const float* b1 = (const float*)d_in[6];
    const float* m1 = (const float*)d_in[7];
    const float* v1 = (const float*)d_in[8];
    const float* g2 = (const float*)d_in[9];
    const float* b2 = (const float*)d_in[10];
    const float* m2 = (const float*)d_in[11];
    const float* v2 = (const float*)d_in[12];

    // ws: gapsum [0,32KB) | xt 16.78MB | o1 16.78MB | kbuf 37.75MB | [kbuf2 37.75MB if room]
    const size_t XT_OFF  = 32768;
    const size_t O1_OFF  = XT_OFF + (size_t)16777216;
    const size_t KB_OFF  = O1_OFF + (size_t)16777216;
    const size_t KSZ     = (size_t)32 * 9 * 65536 * 2;
    const size_t NEED1   = KB_OFF + KSZ;
    const size_t NEED2   = NEED1 + KSZ;
    if (ws_size < NEED1) return;

    char* ws = (char*)d_ws;
    float* gapsum   = (float*)ws;
    ushort_t* xt    = (ushort_t*)(ws + XT_OFF);
    ushort_t* o1    = (ushort_t*)(ws + O1_OFF);
    ushort_t* kbuf  = (ushort_t*)(ws + KB_OFF);
    ushort_t* kbuf2 = (ushort_t*)(ws + NEED1);

    hipMemsetAsync(gapsum, 0, 32768, stream);
    transpose_gap_kernel<<<dim3(32, 8, 32), 256, 0, stream>>>(x, xt, gapsum);
    if (ws_size >= NEED2) {
        combine_kernel2<<<dim3(512, 1, 2), 256, 0, stream>>>(w1, w2, gapsum, rw, rb, kbuf, kbuf2);
        gemm_conv<0><<<512, 256, 0, stream>>>(xt, kbuf, (void*)o1, g1, b1, m1, v1, nullptr);
        gemm_conv<1><<<512, 256, 0, stream>>>(o1, kbuf2, d_out, g2, b2, m2, v2, xt);
    } else {
        combine_kernel2<<<dim3(512, 1, 1), 256, 0, stream>>>(w1, w1, gapsum, rw, rb, kbuf, kbuf);
        gemm_conv<0><<<512, 256, 0, stream>>>(xt, kbuf, (void*)o1, g1, b1, m1, v1, nullptr);
        combine_kernel2<<<dim3(512, 1, 1), 256, 0, stream>>>(w2, w2, gapsum, rw, rb, kbuf, kbuf);
        gemm_conv<1><<<512, 256, 0, stream>>>(o1, kbuf, d_out, g2, b2, m2, v2, xt);
    }
}

// Round 8
// 272.605 us; speedup vs baseline: 1.1616x; 1.1086x over previous
//
#include <hip/hip_runtime.h>

typedef unsigned short ushort_t;
typedef __attribute__((ext_vector_type(8))) __bf16 bf16x8;
typedef __attribute__((ext_vector_type(4))) float f32x4;
typedef __attribute__((ext_vector_type(4))) int i32x4;
typedef __attribute__((ext_vector_type(4))) unsigned short u16x4;

#define BN_EPS 1e-5f
#define EPAD 136  // epilogue [p][c] c-stride (272B row, 16B-aligned)

__device__ __forceinline__ ushort_t f2bf(float f) {
    union { float f; unsigned u; } v; v.f = f;
    unsigned r = v.u + 0x7FFFu + ((v.u >> 16) & 1u);
    return (ushort_t)(r >> 16);
}
__device__ __forceinline__ float bf2f(ushort_t h) {
    union { unsigned u; float f; } v; v.u = ((unsigned)h) << 16; return v.f;
}

// async 16B global->LDS copy; LDS dst is wave-uniform base (+lane*16 by HW)
__device__ __forceinline__ void async_cp16(const ushort_t* g, ushort_t* l) {
    __builtin_amdgcn_global_load_lds(
        (const __attribute__((address_space(1))) unsigned int*)g,
        (__attribute__((address_space(3))) unsigned int*)l, 16, 0, 0);
}

// ---------------- transpose+cast+GAP (round-4 proven form) ----------------
__global__ void transpose_gap_kernel(const float* __restrict__ x, ushort_t* __restrict__ xt,
                                     float* __restrict__ gapsum) {
    __shared__ float tile[32][33];
    int b = blockIdx.z, c0 = blockIdx.y * 32, p0 = blockIdx.x * 32;
    int tx = threadIdx.x & 31, ty = threadIdx.x >> 5; // ty 0..7
    float ps[4];
    #pragma unroll
    for (int i = 0; i < 4; ++i) {
        int c = ty + i * 8;
        float v = x[((long)b * 256 + c0 + c) * 1024 + p0 + tx];
        tile[c][tx] = v;
        ps[i] = v;
    }
    #pragma unroll
    for (int off = 16; off; off >>= 1)
        #pragma unroll
        for (int i = 0; i < 4; ++i) ps[i] += __shfl_down(ps[i], off, 32);
    if (tx == 0)
        #pragma unroll
        for (int i = 0; i < 4; ++i) atomicAdd(&gapsum[b * 256 + c0 + ty + i * 8], ps[i]);
    __syncthreads();
    #pragma unroll
    for (int i = 0; i < 4; ++i) {
        int p = ty + i * 8;
        xt[((long)b * 1024 + p0 + p) * 256 + c0 + tx] = f2bf(tile[tx][p]);
    }
}

// ---------------- router (once): r[b*8+e] = sigmoid(gap.w + b) ----------------
__global__ void router_kernel(const float* __restrict__ gapsum, const float* __restrict__ rw,
                              const float* __restrict__ rb, float* __restrict__ r) {
    int t = threadIdx.x, b = t >> 3, e = t & 7;
    const float* gp = &gapsum[b * 256];
    const float* wp = &rw[e * 256];
    float s = 0.f;
    for (int c = 0; c < 256; ++c) s += gp[c] * wp[c];
    r[t] = 1.f / (1.f + expf(-(s * (1.f / 1024.f) + rb[e])));
}

// ---------------- combine: k[b][pos][g] = sum_e r[b,e]*w[e][g][pos] ----------------
// Block: 128-g tile, all e/p/b. w staged via LDS with coalesced linear loads
// (w contiguous in (g,p) for fixed e); per-thread fragment register-resident
// across the 32-b loop (p-split: ph=0 -> pos 0..3, ph=1 -> pos 4..8; no spill).
__global__ __launch_bounds__(256, 4) void combine_kernel3(
    const float* __restrict__ w1, const float* __restrict__ w2,
    const float* __restrict__ rbuf,
    ushort_t* __restrict__ k1, ushort_t* __restrict__ k2) {
    const float* w = blockIdx.z ? w2 : w1;
    ushort_t* ko = blockIdx.z ? k2 : k1;
    __shared__ float wtile[9216]; // [e][128g * 9p]
    __shared__ float rsh[256];    // [b][e]
    int t = threadIdx.x;
    rsh[t] = rbuf[t];
    const long gbase9 = ((long)blockIdx.x * 128) * 9;
    #pragma unroll
    for (int e = 0; e < 8; ++e) {
        const float* src = w + (long)e * 589824 + gbase9; // e*65536*9
        float* dst = &wtile[e * 1152];
        #pragma unroll
        for (int j = 0; j < 4; ++j) dst[t + j * 256] = src[t + j * 256];
        if (t < 128) dst[t + 1024] = src[t + 1024];
    }
    __syncthreads();
    int gl = t & 127, ph = t >> 7;     // ph wave-uniform
    int pbase = ph ? 4 : 0, np = ph ? 5 : 4;
    float wv[5][8];                    // <=40 live floats
    #pragma unroll
    for (int e = 0; e < 8; ++e)
        for (int p = 0; p < np; ++p)
            wv[p][e] = wtile[e * 1152 + gl * 9 + pbase + p];
    long g = (long)blockIdx.x * 128 + gl;
    for (int b = 0; b < 32; ++b) {
        float rv[8];
        #pragma unroll
        for (int e = 0; e < 8; ++e) rv[e] = rsh[b * 8 + e];
        #pragma unroll
        for (int p = 0; p < 5; ++p) {
            if (p < np) {              // wave-uniform
                float s = 0.f;
                #pragma unroll
                for (int e = 0; e < 8; ++e) s += rv[e] * wv[p][e];
                ko[((long)(b * 9 + pbase + p)) * 65536 + g] = f2bf(s);
            }
        }
    }
}

// ---------------- implicit-GEMM conv 3x3 (pad 1), per-sample weights ----------------
// (round-4 body, verbatim — proven 47.5 us, 0 bank conflicts, VGPR 88)
// Grid: 512 linear blocks, XCD-swizzled: id%8 = b%8 so all 16 (nt,mt) siblings of a
// sample land on one XCD => weight/x L2 reuse.
// LDS (16B chunks, XOR-swizzled, written only by global_load_lds):
//   ldsB: halo [6][34] x 8 k-chunks; slot(pi,j)=pi*8+(j^(pi&7))
//   ldsA: 2 x (128 x 8 k-chunks);    slot(row,j)=row*8+(j^(row&7))
// MODE 0: bf16 relu(bn(conv)) [b][p][c];  MODE 1: f32 relu(bn(conv)+resid) [b][c][p]
template <int MODE>
__global__ __launch_bounds__(256, 2) void gemm_conv(
    const ushort_t* __restrict__ xin,   // [B][1024][256] bf16
    const ushort_t* __restrict__ kbank, // [B][9][256][256] bf16
    void* __restrict__ outp,
    const float* __restrict__ gam, const float* __restrict__ bet,
    const float* __restrict__ mu, const float* __restrict__ var,
    const ushort_t* __restrict__ residt) { // [B][1024][256] bf16 (MODE 1 only)
    __shared__ ushort_t smem[29440]; // ldsB [0,13056) ; ldsA [13056,29440)
    ushort_t* ldsB = smem;
    ushort_t* ldsA = smem + 13056;

    const int t = threadIdx.x;
    const int lane = t & 63;
    const int lane15 = lane & 15;
    const int quad = lane >> 4;
    const int wv = t >> 6;
    const int id = blockIdx.x;           // 0..511
    const int q  = id >> 3;
    const int mt = q & 1;
    const int nt = (q >> 1) & 7;
    const int b  = (id & 7) + ((q >> 4) << 3);
    const int h0 = nt * 4;
    const int p0 = nt * 128;
    const int mw0 = (wv >> 1) * 64;
    const int nw0 = (wv & 1) * 64;
    const int wbase = t & ~63;

    f32x4 acc[4][4];
    #pragma unroll
    for (int i = 0; i < 4; ++i)
        #pragma unroll
        for (int j = 0; j < 4; ++j) acc[i][j] = 0.f;

    // pre-zero border cols w'=0,33 (never overwritten)
    if (t < 96) {
        int rix = t >> 3, j = t & 7;
        int pi = (rix >> 1) * 34 + (rix & 1) * 33;
        i32x4 z = 0;
        *(i32x4*)(&ldsB[(pi * 8 + j) * 8]) = z;
    }
    if (nt == 0) { i32x4 z = 0; *(i32x4*)(&ldsB[(8 + t) * 8]) = z; }
    if (nt == 7) { i32x4 z = 0; *(i32x4*)(&ldsB[((5 * 34 + 1) * 8 + t) * 8]) = z; }

    const long xbase = (long)b * 1024 * 256;
    const long kbase = (long)b * 9 * 65536;

    auto stageB = [&](int kc) {
        #pragma unroll
        for (int hh = 0; hh < 6; ++hh) {
            int hg = h0 + hh - 1;
            if (hg < 0 || hg >= 32) continue; // block-uniform
            int ww = t >> 3;
            int pi = hh * 34 + 1 + ww;
            int jd = (t & 7) ^ (pi & 7);
            async_cp16(xin + xbase + (long)(hg * 32 + ww) * 256 + kc * 64 + jd * 8,
                       ldsB + ((hh * 34 + 1) * 8 + wbase) * 8);
        }
    };
    auto stageA = [&](int kc, int pos, int buf) {
        const ushort_t* srcA = kbank + kbase + (long)pos * 65536 + (long)mt * 32768 + kc * 64;
        ushort_t* base = ldsA + buf * 8192;
        #pragma unroll
        for (int it = 0; it < 4; ++it) {
            int s = it * 256 + t;
            int row = s >> 3;
            int k8 = (s & 7) ^ (row & 7);
            async_cp16(srcA + (long)row * 256 + k8 * 8, base + (it * 256 + wbase) * 8);
        }
    };

    stageB(0);
    stageA(0, 0, 0);
    __syncthreads();

    int par = 0;
    for (int kc = 0; kc < 4; ++kc) {
        for (int pos = 0; pos < 9; ++pos) {
            if (!(kc == 3 && pos == 8)) {
                int nk = kc, np = pos + 1;
                if (np == 9) { np = 0; ++nk; }
                stageA(nk, np, par ^ 1);
            }
            const int dh = pos / 3 - 1, dw = pos % 3 - 1;
            const ushort_t* ab = ldsA + par * 8192;
            #pragma unroll
            for (int kb = 0; kb < 2; ++kb) {
                int jk = kb * 4 + quad;
                bf16x8 af[4], bfr[4];
                #pragma unroll
                for (int mf = 0; mf < 4; ++mf) {
                    int row = mw0 + mf * 16 + lane15;
                    af[mf] = *(const bf16x8*)(ab + (row * 8 + (jk ^ (row & 7))) * 8);
                }
                #pragma unroll
                for (int nf = 0; nf < 4; ++nf) {
                    int n = nw0 + nf * 16 + lane15;
                    int pi = ((n >> 5) + 1 + dh) * 34 + (n & 31) + 1 + dw;
                    bfr[nf] = *(const bf16x8*)(&ldsB[(pi * 8 + (jk ^ (pi & 7))) * 8]);
                }
                #pragma unroll
                for (int mf = 0; mf < 4; ++mf)
                    #pragma unroll
                    for (int nf = 0; nf < 4; ++nf)
                        acc[mf][nf] = __builtin_amdgcn_mfma_f32_16x16x32_bf16(af[mf], bfr[nf], acc[mf][nf], 0, 0, 0);
            }
            __syncthreads(); // reads of buf[par] & B done; prefetched A arrived
            if (pos == 8 && kc < 3) { stageB(kc + 1); __syncthreads(); }
            par ^= 1;
        }
    }

    // residual prefetch (MODE 1): bf16 from xt
    u16x4 rres[4][4];
    if (MODE == 1) {
        #pragma unroll
        for (int mf = 0; mf < 4; ++mf)
            #pragma unroll
            for (int nf = 0; nf < 4; ++nf) {
                int p = p0 + nw0 + nf * 16 + lane15;
                int cb = mt * 128 + mw0 + mf * 16 + quad * 4;
                rres[mf][nf] = *(const u16x4*)(residt + ((long)b * 1024 + p) * 256 + cb);
            }
    }

    float sc[4][4], sh[4][4];
    #pragma unroll
    for (int mf = 0; mf < 4; ++mf)
        #pragma unroll
        for (int i = 0; i < 4; ++i) {
            int c = mt * 128 + mw0 + mf * 16 + quad * 4 + i;
            float s = gam[c] * rsqrtf(var[c] + BN_EPS);
            sc[mf][i] = s;
            sh[mf][i] = bet[c] - mu[c] * s;
        }

    if (MODE == 0) {
        __syncthreads();
        ushort_t* ldsE = smem; // [128 p][EPAD c]
        #pragma unroll
        for (int mf = 0; mf < 4; ++mf)
            #pragma unroll
            for (int nf = 0; nf < 4; ++nf) {
                int pl = nw0 + nf * 16 + lane15;
                int cb = mw0 + mf * 16 + quad * 4;
                u16x4 pk;
                #pragma unroll
                for (int i = 0; i < 4; ++i) {
                    float v = acc[mf][nf][i] * sc[mf][i] + sh[mf][i];
                    pk[i] = f2bf(fmaxf(v, 0.f));
                }
                *(u16x4*)(&ldsE[pl * EPAD + cb]) = pk;
            }
        __syncthreads();
        ushort_t* op = (ushort_t*)outp;
        #pragma unroll
        for (int it = 0; it < 8; ++it) {
            int s = t + it * 256;
            int row = s >> 4, l16 = s & 15;
            i32x4 v = *(i32x4*)(&ldsE[row * EPAD + l16 * 8]);
            *(i32x4*)(op + ((long)b * 1024 + p0 + row) * 256 + mt * 128 + l16 * 8) = v;
        }
    } else {
        float* op = (float*)outp;
        #pragma unroll
        for (int mf = 0; mf < 4; ++mf)
            #pragma unroll
            for (int nf = 0; nf < 4; ++nf) {
                int p = p0 + nw0 + nf * 16 + lane15;
                #pragma unroll
                for (int i = 0; i < 4; ++i) {
                    int c = mt * 128 + mw0 + mf * 16 + quad * 4 + i;
                    float v = acc[mf][nf][i] * sc[mf][i] + sh[mf][i] + bf2f(rres[mf][nf][i]);
                    op[((long)b * 256 + c) * 1024 + p] = fmaxf(v, 0.f);
                }
            }
    }
}

extern "C" void kernel_launch(void* const* d_in, const int* in_sizes, int n_in,
                              void* d_out, int out_size, void* d_ws, size_t ws_size,
                              hipStream_t stream) {
    const float* x  = (const float*)d_in[0];
    const float* rw = (const float*)d_in[1];
    const float* rb = (const float*)d_in[2];
    const float* w1 = (const float*)d_in[3];
    const float* w2 = (const float*)d_in[4];
    const float* g1 = (const float*)d_in[5];
    const float* b1 = (const float*)d_in[6];
    const float* m1 = (const float*)d_in[7];
    const float* v1 = (const float*)d_in[8];
    const float* g2 = (const float*)d_in[9];
    const float* b2 = (const float*)d_in[10];
    const float* m2 = (const float*)d_in[11];
    const float* v2 = (const float*)d_in[12];

    // ws: gapsum [0,32KB) | r [32KB,+1KB) | xt | o1 | kbuf | [kbuf2 if room]
    const size_t R_OFF   = 32768;
    const size_t XT_OFF  = 36864;
    const size_t O1_OFF  = XT_OFF + (size_t)16777216;
    const size_t KB_OFF  = O1_OFF + (size_t)16777216;
    const size_t KSZ     = (size_t)32 * 9 * 65536 * 2;
    const size_t NEED1   = KB_OFF + KSZ;
    const size_t NEED2   = NEED1 + KSZ;
    if (ws_size < NEED1) return;

    char* ws = (char*)d_ws;
    float* gapsum   = (float*)ws;
    float* rbuf     = (float*)(ws + R_OFF);
    ushort_t* xt    = (ushort_t*)(ws + XT_OFF);
    ushort_t* o1    = (ushort_t*)(ws + O1_OFF);
    ushort_t* kbuf  = (ushort_t*)(ws + KB_OFF);
    ushort_t* kbuf2 = (ushort_t*)(ws + NEED1);

    hipMemsetAsync(gapsum, 0, 32768, stream);
    transpose_gap_kernel<<<dim3(32, 8, 32), 256, 0, stream>>>(x, xt, gapsum);
    router_kernel<<<1, 256, 0, stream>>>(gapsum, rw, rb, rbuf);
    if (ws_size >= NEED2) {
        combine_kernel3<<<dim3(512, 1, 2), 256, 0, stream>>>(w1, w2, rbuf, kbuf, kbuf2);
        gemm_conv<0><<<512, 256, 0, stream>>>(xt, kbuf, (void*)o1, g1, b1, m1, v1, nullptr);
        gemm_conv<1><<<512, 256, 0, stream>>>(o1, kbuf2, d_out, g2, b2, m2, v2, xt);
    } else {
        combine_kernel3<<<dim3(512, 1, 1), 256, 0, stream>>>(w1, w1, rbuf, kbuf, kbuf);
        gemm_conv<0><<<512, 256, 0, stream>>>(xt, kbuf, (void*)o1, g1, b1, m1, v1, nullptr);
        combine_kernel3<<<dim3(512, 1, 1), 256, 0, stream>>>(w2, w2, rbuf, kbuf, kbuf);
        gemm_conv<1><<<512, 256, 0, stream>>>(o1, kbuf, d_out, g2, b2, m2, v2, xt);
    }
}